// Round 3
// baseline (3005.392 us; speedup 1.0000x reference)
//
#include <hip/hip_runtime.h>
#include <hip/hip_bf16.h>
#include <math.h>

#define B_    4
#define CDIM  128
#define Hh    256
#define Ww    256
#define SD_   64
#define FD_   32
#define HW    (Hh*Ww)
#define NPOS  (B_*HW)

typedef __hip_bfloat16 bf16;

__device__ __forceinline__ bf16 f2b(float f){ return __float2bfloat16(f); }
__device__ __forceinline__ float b2f(bf16 h){ return __bfloat162float(h); }
__device__ __forceinline__ unsigned short f2us(float f){
  __hip_bfloat16 h=__float2bfloat16(f);
  return *reinterpret_cast<unsigned short*>(&h);
}
__device__ __forceinline__ float us2f(unsigned short u){
  unsigned int i=((unsigned int)u)<<16;
  return __uint_as_float(i);
}

// ---------------- K1: inverse RMS over 128 channels per position ----------------
__global__ __launch_bounds__(256) void k_invr(const float* __restrict__ x, float* __restrict__ invr){
  const int p=blockIdx.x*256+threadIdx.x;
  const int b=p/HW, rem=p-b*HW;
  const float* xp=x+(size_t)b*CDIM*HW+rem;
  float s=0.f;
  #pragma unroll 4
  for(int c=0;c<CDIM;c++){ float v=xp[(size_t)c*HW]; s+=v*v; }
  invr[p]=rsqrtf(s*(1.f/CDIM)+1e-6f);
}

// ---------------- K2: qpre/kpre/v = wq/wk/wv . xs ----------------
__global__ __launch_bounds__(256) void k_qkv(const float* __restrict__ x, const float* __restrict__ invr,
    const float* __restrict__ n1s, const float* __restrict__ wq, const float* __restrict__ wk,
    const float* __restrict__ wv,
    bf16* __restrict__ qpre, bf16* __restrict__ kpre, bf16* __restrict__ vout)
{
  __shared__ __align__(16) char smem[65536];
  float* xs  =(float*)smem;             // [64][64]
  float* wql =(float*)(smem+16384);
  float* wkl =(float*)(smem+32768);
  float* wvl =(float*)(smem+49152);
  const int t=threadIdx.x;
  const int p0=blockIdx.x*64;
  const int b=p0/HW, rem0=p0-b*HW;
  for(int i=t;i<4096;i+=256){ wql[i]=wq[i]; wkl[i]=wk[i]; wvl[i]=wv[i]; }
  for(int i=t;i<4096;i+=256){
    int ci=i>>6,p=i&63;
    xs[i]=x[(size_t)(b*CDIM+ci)*HW+rem0+p]*invr[p0+p]*n1s[ci];
  }
  __syncthreads();
  for(int pass=0;pass<16;pass++){
    int co=pass*4+(t>>6);
    int p=t&63;
    float aq=0.f,ak=0.f,av=0.f;
    #pragma unroll 8
    for(int ci=0;ci<64;ci++){
      float xv=xs[ci*64+p];
      aq+=wql[co*64+ci]*xv; ak+=wkl[co*64+ci]*xv; av+=wvl[co*64+ci]*xv;
    }
    size_t off=(size_t)(b*SD_+co)*HW+rem0+p;
    qpre[off]=f2b(aq); kpre[off]=f2b(ak); vout[off]=f2b(av);
  }
}

// ---------------- K3: depthwise 3x3 on qpre/kpre, elu+1, kv/denom reduce ----------------
__global__ __launch_bounds__(256) void k_spatial(const bf16* __restrict__ qpre, const bf16* __restrict__ kpre,
  const bf16* __restrict__ vin, const float* __restrict__ dwqk,
  bf16* __restrict__ qout, float* __restrict__ kvsum, float* __restrict__ densum)
{
  const int blk=blockIdx.x;               // (b*64+c)*256 + h
  const int h=blk&255, bc=blk>>8, c=bc&63;
  const int t=threadIdx.x;
  __shared__ float qr[3][264], kr[3][264];
  __shared__ float pkv[4], pk[4];
  const size_t base=(size_t)bc*HW;
  #pragma unroll
  for(int r=0;r<3;r++){
    int hr=h+r-1;
    float qv=0.f,kv2=0.f;
    if(hr>=0&&hr<Hh){ qv=b2f(qpre[base+(size_t)hr*Ww+t]); kv2=b2f(kpre[base+(size_t)hr*Ww+t]); }
    qr[r][t+1]=qv; kr[r][t+1]=kv2;
  }
  if(t==0){
    #pragma unroll
    for(int r=0;r<3;r++){ qr[r][0]=0.f;kr[r][0]=0.f;qr[r][257]=0.f;kr[r][257]=0.f; }
  }
  __syncthreads();
  const float* dwc=dwqk+c*9;
  float d0=dwc[0],d1=dwc[1],d2=dwc[2],d3=dwc[3],d4=dwc[4],d5=dwc[5],d6=dwc[6],d7=dwc[7],d8=dwc[8];
  float qa = qr[0][t]*d0+qr[0][t+1]*d1+qr[0][t+2]*d2
           + qr[1][t]*d3+qr[1][t+1]*d4+qr[1][t+2]*d5
           + qr[2][t]*d6+qr[2][t+1]*d7+qr[2][t+2]*d8;
  float ka = kr[0][t]*d0+kr[0][t+1]*d1+kr[0][t+2]*d2
           + kr[1][t]*d3+kr[1][t+1]*d4+kr[1][t+2]*d5
           + kr[2][t]*d6+kr[2][t+1]*d7+kr[2][t+2]*d8;
  float qq = qa>0.f? qa+1.f: expf(qa);   // elu+1
  float kk = ka>0.f? ka+1.f: expf(ka);
  qout[base+(size_t)h*Ww+t]=f2b(qq);
  float vv=b2f(vin[base+(size_t)h*Ww+t]);
  float s1=kk*vv, s2=kk;
  #pragma unroll
  for(int off=32;off>0;off>>=1){ s1+=__shfl_down(s1,off,64); s2+=__shfl_down(s2,off,64); }
  const int wid=t>>6, lane=t&63;
  if(lane==0){ pkv[wid]=s1; pk[wid]=s2; }
  __syncthreads();
  if(t==0){
    atomicAdd(&kvsum[bc], pkv[0]+pkv[1]+pkv[2]+pkv[3]);
    atomicAdd(&densum[bc], pk[0]+pk[1]+pk[2]+pk[3]);
  }
}

// ---------------- K4: frequency branch == a*x + b*rowHilbert(x) ----------------
__global__ __launch_bounds__(256) void k_hil(const float* __restrict__ x, const float* __restrict__ invr,
  const float* __restrict__ n1s, const float* __restrict__ cw, bf16* __restrict__ xfsp)
{
  const int blk=blockIdx.x;               // (b*32+cf)*256 + h
  const int h=blk&255, bcf=blk>>8, cf=bcf&31, b=bcf>>5;
  const int t=threadIdx.x;
  __shared__ float xr[256];
  __shared__ float tap[128];
  const int c=SD_+cf;
  const size_t rowx=(size_t)(b*CDIM+c)*HW+(size_t)h*Ww;
  const size_t rowp=(size_t)b*HW+(size_t)h*Ww;
  xr[t]=x[rowx+t]*invr[rowp+t]*n1s[c];
  if(t<128){
    int d=2*t+1;
    float dd = (d<128)? (float)d : (float)(256-d);
    float sg = (d<128)? -1.f : 1.f;
    float a=dd*(float)(3.14159265358979323846/256.0);
    tap[t]=sg*(1.f/128.f)*(cosf(a)/sinf(a));    // m[d] = -(2/W)cot(pi d/W), odd d
  }
  __syncthreads();
  float acc=0.f;
  #pragma unroll 8
  for(int j=0;j<128;j++){
    acc+=tap[j]*xr[(t-(2*j+1))&255];
  }
  float a_=cw[2*cf], b_=cw[2*cf+1];
  xfsp[(size_t)(b*FD_+cf)*HW+(size_t)h*Ww+t]=f2b(a_*xr[t]+b_*acc);
}

// ---------------- K5: gate + freq-norm + combine + proj + rmsnorm2 + MLP ----------------
__global__ __launch_bounds__(256) void k_main(
  const float* __restrict__ x, const float* __restrict__ invr, const float* __restrict__ n1s,
  const bf16* __restrict__ q, const bf16* __restrict__ v, const bf16* __restrict__ xfsp,
  const float* __restrict__ kvsum, const float* __restrict__ densum,
  const float* __restrict__ relb, const float* __restrict__ sscale,
  const float* __restrict__ fnorm, const float* __restrict__ freq_w, const float* __restrict__ gate_w,
  const float* __restrict__ projw, const float* __restrict__ n2s,
  const float* __restrict__ w1, const float* __restrict__ w2,
  bf16* __restrict__ h2)
{
  __shared__ __align__(16) char smem[65536];
  float* comb =(float*)smem;             // [128][64]        (later overlaid by hid)
  float* pr   =(float*)(smem+32768);     // [128][64]        (after proj)
  float* xfs  =(float*)(smem+32768);     // [32][64]  pre-proj only
  float* gsh  =(float*)(smem+40960);     // [32][64]  pre-proj only
  float* xg   =(float*)(smem+49152);     // [32][64]  pre-proj only
  float* invp =(float*)(smem+57344);     // [64]      pre-proj only
  float* invp2=(float*)smem;             // [64]      (comb region, post-proj)
  unsigned short* hid=(unsigned short*)smem; // [256][64] bf16 (comb region, post-rescale)

  const int t=threadIdx.x;
  const int p0=blockIdx.x*64;
  const int b=p0/HW;
  const int rem0=p0-b*HW;

  for(int i=t;i<2048;i+=256){
    int ci=i>>6,p=i&63;
    xfs[i]=b2f(xfsp[(size_t)(b*FD_+ci)*HW+rem0+p]);
    xg[i] =x[(size_t)(b*CDIM+96+ci)*HW+rem0+p]*invr[p0+p]*n1s[96+ci];
  }
  __syncthreads();
  if(t<64){
    float s=0.f;
    #pragma unroll
    for(int ci=0;ci<32;ci++){ float vv=xfs[ci*64+t]; s+=vv*vv; }
    invp[t]=rsqrtf(s*(1.f/32.f)+1e-6f);
  }
  __syncthreads();
  // gate matvec + sigmoid
  for(int i=t;i<2048;i+=256){
    int co=i>>6,p=i&63;
    int cou=__builtin_amdgcn_readfirstlane(co);
    float acc=0.f;
    #pragma unroll
    for(int ci=0;ci<32;ci+=4){
      float4 w4=*(const float4*)(gate_w+cou*32+ci);
      acc+=w4.x*xg[ci*64+p]+w4.y*xg[(ci+1)*64+p]+w4.z*xg[(ci+2)*64+p]+w4.w*xg[(ci+3)*64+p];
    }
    gsh[i]=1.f/(1.f+expf(-acc));
  }
  // fold fnorm rmsnorm into xfs
  for(int i=t;i<2048;i+=256){
    int ci=i>>6,p=i&63;
    xfs[i]*=invp[p]*fnorm[ci];
  }
  __syncthreads();
  // build combined (gated) 128 channels
  const float ss=sscale[0];
  for(int i=t;i<8192;i+=256){
    int c=i>>6,p=i&63;
    float g=gsh[(c&31)*64+p];
    float val;
    if(c<64){
      size_t off=(size_t)(b*SD_+c)*HW+rem0+p;
      float kvv=kvsum[b*SD_+c];
      float dd=densum[b*SD_+c]+1e-6f;
      val=(b2f(q[off])*kvv/dd + b2f(v[off]))*(ss+relb[c]);
    } else if(c<96){
      int cou=__builtin_amdgcn_readfirstlane(c-64);
      float acc=0.f;
      #pragma unroll
      for(int ci=0;ci<32;ci+=4){
        float4 w4=*(const float4*)(freq_w+cou*32+ci);
        acc+=w4.x*xfs[ci*64+p]+w4.y*xfs[(ci+1)*64+p]+w4.z*xfs[(ci+2)*64+p]+w4.w*xfs[(ci+3)*64+p];
      }
      val=acc;
    } else {
      val=1.f;
    }
    comb[i]=val*g;
  }
  __syncthreads();
  // proj 128x128
  for(int pass=0;pass<32;pass++){
    int co=pass*4+(t>>6);
    int cou=__builtin_amdgcn_readfirstlane(co);
    int p=t&63;
    float acc=0.f;
    #pragma unroll 8
    for(int ci=0;ci<128;ci+=4){
      float4 w4=*(const float4*)(projw+cou*128+ci);
      acc+=w4.x*comb[ci*64+p]+w4.y*comb[(ci+1)*64+p]+w4.z*comb[(ci+2)*64+p]+w4.w*comb[(ci+3)*64+p];
    }
    pr[cou*64+p]=acc;
  }
  __syncthreads();
  if(t<64){
    float s=0.f;
    for(int c=0;c<CDIM;c++){ float vv=pr[c*64+t]; s+=vv*vv; }
    invp2[t]=rsqrtf(s*(1.f/128.f)+1e-6f);
  }
  __syncthreads();
  for(int i=t;i<8192;i+=256){
    int c=i>>6,p=i&63;
    pr[i]*=invp2[p]*n2s[c];
  }
  __syncthreads();
  // mlp1 + exact gelu -> hid (bf16)
  for(int pass=0;pass<64;pass++){
    int ho=pass*4+(t>>6);
    int hou=__builtin_amdgcn_readfirstlane(ho);
    int p=t&63;
    float acc=0.f;
    #pragma unroll 8
    for(int ci=0;ci<128;ci+=4){
      float4 w4=*(const float4*)(w1+hou*128+ci);
      acc+=w4.x*pr[ci*64+p]+w4.y*pr[(ci+1)*64+p]+w4.z*pr[(ci+2)*64+p]+w4.w*pr[(ci+3)*64+p];
    }
    float ge=0.5f*acc*(1.f+erff(acc*0.70710678118654752f));
    hid[hou*64+p]=f2us(ge);
  }
  __syncthreads();
  // mlp2 -> h2 global
  for(int pass=0;pass<32;pass++){
    int co=pass*4+(t>>6);
    int cou=__builtin_amdgcn_readfirstlane(co);
    int p=t&63;
    float acc=0.f;
    #pragma unroll 8
    for(int ho=0;ho<256;ho+=4){
      float4 w4=*(const float4*)(w2+cou*256+ho);
      acc+=w4.x*us2f(hid[ho*64+p])+w4.y*us2f(hid[(ho+1)*64+p])+w4.z*us2f(hid[(ho+2)*64+p])+w4.w*us2f(hid[(ho+3)*64+p]);
    }
    h2[(size_t)(b*CDIM+cou)*HW+rem0+p]=f2b(acc);
  }
}

// ---------------- K6: final depthwise 3x3 + residual ----------------
__global__ __launch_bounds__(256) void k_final(const bf16* __restrict__ h2, const float* __restrict__ x,
  const float* __restrict__ mdw, float* __restrict__ out)
{
  const int blk=blockIdx.x;               // (b*128+c)*256 + h
  const int h=blk&255, bc=blk>>8, c=bc&127;
  const int t=threadIdx.x;
  __shared__ float rr[3][264];
  const size_t base=(size_t)bc*HW;
  #pragma unroll
  for(int r=0;r<3;r++){
    int hr=h+r-1; float vv=0.f;
    if(hr>=0&&hr<Hh) vv=b2f(h2[base+(size_t)hr*Ww+t]);
    rr[r][t+1]=vv;
  }
  if(t==0){
    #pragma unroll
    for(int r=0;r<3;r++){ rr[r][0]=0.f; rr[r][257]=0.f; }
  }
  __syncthreads();
  const float* dwc=mdw+c*9;
  float acc = rr[0][t]*dwc[0]+rr[0][t+1]*dwc[1]+rr[0][t+2]*dwc[2]
            + rr[1][t]*dwc[3]+rr[1][t+1]*dwc[4]+rr[1][t+2]*dwc[5]
            + rr[2][t]*dwc[6]+rr[2][t+1]*dwc[7]+rr[2][t+2]*dwc[8];
  size_t o=base+(size_t)h*Ww+t;
  out[o]=acc+x[o];
}

// ---------------- workspace layout (bytes) ----------------
static const size_t O_INVR = 0;                       // 1 MiB  (B*HW f32)
static const size_t O_V    = (size_t)1<<20;           // 32 MiB bf16
static const size_t O_Q    = O_V    + (size_t)33554432;
static const size_t O_QPRE = O_Q    + (size_t)33554432;
static const size_t O_KPRE = O_QPRE + (size_t)33554432;
static const size_t O_XFSP = O_KPRE + (size_t)33554432; // 16 MiB bf16
static const size_t O_KV   = O_XFSP + (size_t)16777216;
static const size_t O_DEN  = O_KV   + 4096;
static const size_t O_H2   = O_QPRE;                  // reuse qpre+kpre (64 MiB) for h2 bf16

extern "C" void kernel_launch(void* const* d_in, const int* in_sizes, int n_in,
                              void* d_out, int out_size, void* d_ws, size_t ws_size,
                              hipStream_t stream)
{
  const float* x     =(const float*)d_in[0];
  const float* n1s   =(const float*)d_in[1];
  const float* wq    =(const float*)d_in[2];
  const float* wk    =(const float*)d_in[3];
  const float* wv    =(const float*)d_in[4];
  const float* dwqk  =(const float*)d_in[5];
  const float* relb  =(const float*)d_in[6];
  const float* sscale=(const float*)d_in[7];
  const float* cw    =(const float*)d_in[8];
  const float* fnorm =(const float*)d_in[9];
  const float* freq_w=(const float*)d_in[10];
  const float* gate_w=(const float*)d_in[11];
  const float* projw =(const float*)d_in[12];
  const float* n2s   =(const float*)d_in[13];
  const float* w1    =(const float*)d_in[14];
  const float* w2    =(const float*)d_in[15];
  const float* mdw   =(const float*)d_in[16];

  char* ws=(char*)d_ws;
  float* invr =(float*)(ws+O_INVR);
  bf16* v    =(bf16*)(ws+O_V);
  bf16* q    =(bf16*)(ws+O_Q);
  bf16* qpre =(bf16*)(ws+O_QPRE);
  bf16* kpre =(bf16*)(ws+O_KPRE);
  bf16* xfsp =(bf16*)(ws+O_XFSP);
  float* kvsum=(float*)(ws+O_KV);
  float* densum=(float*)(ws+O_DEN);
  bf16* h2   =(bf16*)(ws+O_H2);
  float* out =(float*)d_out;

  k_invr<<<dim3(NPOS/256),dim3(256),0,stream>>>(x,invr);
  k_qkv<<<dim3(NPOS/64),dim3(256),0,stream>>>(x,invr,n1s,wq,wk,wv,qpre,kpre,v);
  hipMemsetAsync(ws+O_KV,0,8192,stream);
  k_spatial<<<dim3(B_*SD_*Hh),dim3(256),0,stream>>>(qpre,kpre,v,dwqk,q,kvsum,densum);
  k_hil<<<dim3(B_*FD_*Hh),dim3(256),0,stream>>>(x,invr,n1s,cw,xfsp);
  k_main<<<dim3(NPOS/64),dim3(256),0,stream>>>(x,invr,n1s,q,v,xfsp,kvsum,densum,
                                               relb,sscale,fnorm,freq_w,gate_w,projw,n2s,w1,w2,h2);
  k_final<<<dim3(B_*CDIM*Hh),dim3(256),0,stream>>>(h2,x,mdw,out);
}

// Round 4
// 1341.896 us; speedup vs baseline: 2.2397x; 2.2397x over previous
//
#include <hip/hip_runtime.h>
#include <hip/hip_bf16.h>
#include <math.h>

#define B_    4
#define CDIM  128
#define Hh    256
#define Ww    256
#define SD_   64
#define FD_   32
#define HW    (Hh*Ww)
#define NPOS  (B_*HW)

typedef __hip_bfloat16 bf16;
typedef __attribute__((ext_vector_type(8))) short short8;
typedef __attribute__((ext_vector_type(4))) float f32x4;

__device__ __forceinline__ bf16 f2b(float f){ return __float2bfloat16(f); }
__device__ __forceinline__ float b2f(bf16 h){ return __bfloat162float(h); }
__device__ __forceinline__ unsigned short f2us(float f){
  __hip_bfloat16 h=__float2bfloat16(f);
  return *reinterpret_cast<unsigned short*>(&h);
}
__device__ __forceinline__ float us2f(unsigned short u){
  unsigned int i=((unsigned int)u)<<16;
  return __uint_as_float(i);
}

// ---------------- K0: repack proj/w1/w2 weights into bf16 MFMA A-fragment order ----------------
// dst[((cb*NKS+ks)*64+lane)*8+e] = W[cb*16 + (lane&15)][ks*32 + (lane>>4)*8 + e]
__global__ __launch_bounds__(256) void k_prep(const float* __restrict__ projw,
   const float* __restrict__ w1, const float* __restrict__ w2,
   bf16* __restrict__ pw_f, bf16* __restrict__ w1_f, bf16* __restrict__ w2_f)
{
  int idx=blockIdx.x*256+threadIdx.x;
  const float* src; bf16* dst; int NKS,K,rel;
  if(idx<16384){ src=projw; dst=pw_f; NKS=4; K=128; rel=idx; }
  else if(idx<49152){ src=w1; dst=w1_f; NKS=4; K=128; rel=idx-16384; }
  else { src=w2; dst=w2_f; NKS=8; K=256; rel=idx-49152; }
  int e=rel&7, lane=(rel>>3)&63, rest=rel>>9;
  int ks=rest%NKS, cb=rest/NKS;
  int row=cb*16+(lane&15);
  int k=ks*32+(lane>>4)*8+e;
  dst[rel]=f2b(src[row*K+k]);
}

// ---------------- K1: inverse RMS over 128 channels per position ----------------
__global__ __launch_bounds__(256) void k_invr(const float* __restrict__ x, float* __restrict__ invr){
  const int p=blockIdx.x*256+threadIdx.x;
  const int b=p/HW, rem=p-b*HW;
  const float* xp=x+(size_t)b*CDIM*HW+rem;
  float s=0.f;
  #pragma unroll 4
  for(int c=0;c<CDIM;c++){ float v=xp[(size_t)c*HW]; s+=v*v; }
  invr[p]=rsqrtf(s*(1.f/CDIM)+1e-6f);
}

// ---------------- K2: qpre/kpre/v = wq/wk/wv . xs ----------------
__global__ __launch_bounds__(256) void k_qkv(const float* __restrict__ x, const float* __restrict__ invr,
    const float* __restrict__ n1s, const float* __restrict__ wq, const float* __restrict__ wk,
    const float* __restrict__ wv,
    bf16* __restrict__ qpre, bf16* __restrict__ kpre, bf16* __restrict__ vout)
{
  __shared__ __align__(16) char smem[65536];
  float* xs  =(float*)smem;             // [64][64]
  float* wql =(float*)(smem+16384);
  float* wkl =(float*)(smem+32768);
  float* wvl =(float*)(smem+49152);
  const int t=threadIdx.x;
  const int p0=blockIdx.x*64;
  const int b=p0/HW, rem0=p0-b*HW;
  for(int i=t;i<4096;i+=256){ wql[i]=wq[i]; wkl[i]=wk[i]; wvl[i]=wv[i]; }
  for(int i=t;i<4096;i+=256){
    int ci=i>>6,p=i&63;
    xs[i]=x[(size_t)(b*CDIM+ci)*HW+rem0+p]*invr[p0+p]*n1s[ci];
  }
  __syncthreads();
  for(int pass=0;pass<16;pass++){
    int co=pass*4+(t>>6);
    int p=t&63;
    float aq=0.f,ak=0.f,av=0.f;
    #pragma unroll 8
    for(int ci=0;ci<64;ci++){
      float xv=xs[ci*64+p];
      aq+=wql[co*64+ci]*xv; ak+=wkl[co*64+ci]*xv; av+=wvl[co*64+ci]*xv;
    }
    size_t off=(size_t)(b*SD_+co)*HW+rem0+p;
    qpre[off]=f2b(aq); kpre[off]=f2b(ak); vout[off]=f2b(av);
  }
}

// ---------------- K3: depthwise 3x3 on qpre/kpre, elu+1, kv/denom reduce ----------------
__global__ __launch_bounds__(256) void k_spatial(const bf16* __restrict__ qpre, const bf16* __restrict__ kpre,
  const bf16* __restrict__ vin, const float* __restrict__ dwqk,
  bf16* __restrict__ qout, float* __restrict__ kvsum, float* __restrict__ densum)
{
  const int blk=blockIdx.x;               // (b*64+c)*256 + h
  const int h=blk&255, bc=blk>>8, c=bc&63;
  const int t=threadIdx.x;
  __shared__ float qr[3][264], kr[3][264];
  __shared__ float pkv[4], pk[4];
  const size_t base=(size_t)bc*HW;
  #pragma unroll
  for(int r=0;r<3;r++){
    int hr=h+r-1;
    float qv=0.f,kv2=0.f;
    if(hr>=0&&hr<Hh){ qv=b2f(qpre[base+(size_t)hr*Ww+t]); kv2=b2f(kpre[base+(size_t)hr*Ww+t]); }
    qr[r][t+1]=qv; kr[r][t+1]=kv2;
  }
  if(t==0){
    #pragma unroll
    for(int r=0;r<3;r++){ qr[r][0]=0.f;kr[r][0]=0.f;qr[r][257]=0.f;kr[r][257]=0.f; }
  }
  __syncthreads();
  const float* dwc=dwqk+c*9;
  float d0=dwc[0],d1=dwc[1],d2=dwc[2],d3=dwc[3],d4=dwc[4],d5=dwc[5],d6=dwc[6],d7=dwc[7],d8=dwc[8];
  float qa = qr[0][t]*d0+qr[0][t+1]*d1+qr[0][t+2]*d2
           + qr[1][t]*d3+qr[1][t+1]*d4+qr[1][t+2]*d5
           + qr[2][t]*d6+qr[2][t+1]*d7+qr[2][t+2]*d8;
  float ka = kr[0][t]*d0+kr[0][t+1]*d1+kr[0][t+2]*d2
           + kr[1][t]*d3+kr[1][t+1]*d4+kr[1][t+2]*d5
           + kr[2][t]*d6+kr[2][t+1]*d7+kr[2][t+2]*d8;
  float qq = qa>0.f? qa+1.f: expf(qa);   // elu+1
  float kk = ka>0.f? ka+1.f: expf(ka);
  qout[base+(size_t)h*Ww+t]=f2b(qq);
  float vv=b2f(vin[base+(size_t)h*Ww+t]);
  float s1=kk*vv, s2=kk;
  #pragma unroll
  for(int off=32;off>0;off>>=1){ s1+=__shfl_down(s1,off,64); s2+=__shfl_down(s2,off,64); }
  const int wid=t>>6, lane=t&63;
  if(lane==0){ pkv[wid]=s1; pk[wid]=s2; }
  __syncthreads();
  if(t==0){
    atomicAdd(&kvsum[bc], pkv[0]+pkv[1]+pkv[2]+pkv[3]);
    atomicAdd(&densum[bc], pk[0]+pk[1]+pk[2]+pk[3]);
  }
}

// ---------------- K4: frequency branch == a*x + b*rowHilbert(x) ----------------
__global__ __launch_bounds__(256) void k_hil(const float* __restrict__ x, const float* __restrict__ invr,
  const float* __restrict__ n1s, const float* __restrict__ cw, bf16* __restrict__ xfsp)
{
  const int blk=blockIdx.x;               // (b*32+cf)*256 + h
  const int h=blk&255, bcf=blk>>8, cf=bcf&31, b=bcf>>5;
  const int t=threadIdx.x;
  __shared__ float xr[256];
  __shared__ float tap[128];
  const int c=SD_+cf;
  const size_t rowx=(size_t)(b*CDIM+c)*HW+(size_t)h*Ww;
  const size_t rowp=(size_t)b*HW+(size_t)h*Ww;
  xr[t]=x[rowx+t]*invr[rowp+t]*n1s[c];
  if(t<128){
    int d=2*t+1;
    float dd = (d<128)? (float)d : (float)(256-d);
    float sg = (d<128)? -1.f : 1.f;
    float a=dd*(float)(3.14159265358979323846/256.0);
    tap[t]=sg*(1.f/128.f)*(cosf(a)/sinf(a));    // m[d] = -(2/W)cot(pi d/W), odd d
  }
  __syncthreads();
  float acc=0.f;
  #pragma unroll 8
  for(int j=0;j<128;j++){
    acc+=tap[j]*xr[(t-(2*j+1))&255];
  }
  float a_=cw[2*cf], b_=cw[2*cf+1];
  xfsp[(size_t)(b*FD_+cf)*HW+(size_t)h*Ww+t]=f2b(a_*xr[t]+b_*acc);
}

// ---------------- K5: gate + freq-norm + combine + MFMA proj/rmsnorm2/MLP ----------------
// LDS map (48KB):
//   bt/comb/pr: [pos][128ch] bf16, 256B rows, bytes 0..16384, XOR swizzle ^((pos&7)<<4)
//   hid:        [pos][256ch] bf16, 512B rows, bytes 16384..49152, same swizzle
//   front (dead after barrier 4, overlays hid region):
//     xg @16384 (8KB), invp @24576 (256B), xfs @32768 (8KB), gsh @40960 (8KB)
__global__ __launch_bounds__(256) void k_main(
  const float* __restrict__ x, const float* __restrict__ invr, const float* __restrict__ n1s,
  const bf16* __restrict__ q, const bf16* __restrict__ v, const bf16* __restrict__ xfsp,
  const float* __restrict__ kvsum, const float* __restrict__ densum,
  const float* __restrict__ relb, const float* __restrict__ sscale,
  const float* __restrict__ fnorm, const float* __restrict__ freq_w, const float* __restrict__ gate_w,
  const bf16* __restrict__ pw_f, const float* __restrict__ n2s,
  const bf16* __restrict__ w1_f, const bf16* __restrict__ w2_f,
  bf16* __restrict__ h2)
{
  __shared__ __align__(16) char smem[49152];
  float* xg  =(float*)(smem+16384);
  float* invp=(float*)(smem+24576);
  float* xfs =(float*)(smem+32768);
  float* gsh =(float*)(smem+40960);

  const int t=threadIdx.x;
  const int p0=blockIdx.x*64;
  const int b=p0/HW;
  const int rem0=p0-b*HW;

  // phase 1: load xfs (freq spatial) + xg (gate input)
  for(int i=t;i<2048;i+=256){
    int ci=i>>6,p=i&63;
    xfs[i]=b2f(xfsp[(size_t)(b*FD_+ci)*HW+rem0+p]);
    xg[i] =x[(size_t)(b*CDIM+96+ci)*HW+rem0+p]*invr[p0+p]*n1s[96+ci];
  }
  __syncthreads();
  // phase 2: fnorm inv-rms + gate matvec
  if(t<64){
    float s=0.f;
    #pragma unroll
    for(int ci=0;ci<32;ci++){ float vv=xfs[ci*64+t]; s+=vv*vv; }
    invp[t]=rsqrtf(s*(1.f/32.f)+1e-6f);
  }
  for(int i=t;i<2048;i+=256){
    int co=i>>6,p=i&63;
    int cou=__builtin_amdgcn_readfirstlane(co);
    float acc=0.f;
    #pragma unroll
    for(int ci=0;ci<32;ci+=4){
      float4 w4=*(const float4*)(gate_w+cou*32+ci);
      acc+=w4.x*xg[ci*64+p]+w4.y*xg[(ci+1)*64+p]+w4.z*xg[(ci+2)*64+p]+w4.w*xg[(ci+3)*64+p];
    }
    gsh[i]=1.f/(1.f+expf(-acc));
  }
  __syncthreads();
  // phase 3: fold fnorm rmsnorm into xfs
  for(int i=t;i<2048;i+=256){
    int ci=i>>6,p=i&63;
    xfs[i]*=invp[p]*fnorm[ci];
  }
  __syncthreads();
  // phase 4: combine 128 gated channels -> bt (bf16, swizzled)
  const float ss=sscale[0];
  for(int i=t;i<8192;i+=256){
    int c=i>>6,p=i&63;
    float g=gsh[(c&31)*64+p];
    float val;
    if(c<64){
      size_t off=(size_t)(b*SD_+c)*HW+rem0+p;
      float kvv=kvsum[b*SD_+c];
      float dd=densum[b*SD_+c]+1e-6f;
      val=(b2f(q[off])*kvv/dd + b2f(v[off]))*(ss+relb[c]);
    } else if(c<96){
      int cou=__builtin_amdgcn_readfirstlane(c-64);
      float acc=0.f;
      #pragma unroll
      for(int ci=0;ci<32;ci+=4){
        float4 w4=*(const float4*)(freq_w+cou*32+ci);
        acc+=w4.x*xfs[ci*64+p]+w4.y*xfs[(ci+1)*64+p]+w4.z*xfs[(ci+2)*64+p]+w4.w*xfs[(ci+3)*64+p];
      }
      val=acc;
    } else {
      val=1.f;
    }
    *(unsigned short*)(smem + ((p<<8) + ((c*2) ^ ((p&7)<<4)))) = f2us(val*g);
  }
  __syncthreads();
  // ---- wave-private MFMA tail (each wave owns 16 positions; no more barriers) ----
  const int l=t&63, w=t>>6;
  const int ploc=w*16+(l&15);           // this lane's B-column position
  const int lg=l>>4;                    // lane group (k sub-block / C row group)
  const int psw=(ploc&7)<<4;            // XOR swizzle for this row

  // proj: B-frags from comb
  short8 bf[4];
  #pragma unroll
  for(int ks=0;ks<4;ks++){
    int kb=ks*64+lg*16;
    bf[ks]=*(const short8*)(smem + ((ploc<<8) + (kb ^ psw)));
  }
  f32x4 acc[8];
  #pragma unroll
  for(int cb=0;cb<8;cb++){
    f32x4 a={0.f,0.f,0.f,0.f};
    #pragma unroll
    for(int ks=0;ks<4;ks++){
      short8 af=*(const short8*)(pw_f + (size_t)((cb*4+ks)*64+l)*8);
      a=__builtin_amdgcn_mfma_f32_16x16x32_bf16(af,bf[ks],a,0,0,0);
    }
    acc[cb]=a;
  }
  // rmsnorm2 in-register: sum squares over 128 channels of this position
  float s2=0.f;
  #pragma unroll
  for(int cb=0;cb<8;cb++){
    s2+=acc[cb][0]*acc[cb][0]+acc[cb][1]*acc[cb][1]+acc[cb][2]*acc[cb][2]+acc[cb][3]*acc[cb][3];
  }
  s2+=__shfl_xor(s2,16);
  s2+=__shfl_xor(s2,32);
  float inv2=rsqrtf(s2*(1.f/128.f)+1e-6f);
  // scale + write pr (overwrites comb rows of this wave only)
  #pragma unroll
  for(int cb=0;cb<8;cb++){
    int c0=cb*16+lg*4;
    float4 nv=*(const float4*)(n2s+c0);
    float v0=acc[cb][0]*inv2*nv.x, v1=acc[cb][1]*inv2*nv.y;
    float v2=acc[cb][2]*inv2*nv.z, v3=acc[cb][3]*inv2*nv.w;
    unsigned u01=(unsigned)f2us(v0) | (((unsigned)f2us(v1))<<16);
    unsigned u23=(unsigned)f2us(v2) | (((unsigned)f2us(v3))<<16);
    int base=(ploc<<8) + ((c0*2) ^ psw);
    *(unsigned*)(smem+base)=u01;
    *(unsigned*)(smem+base+4)=u23;
  }
  // mlp1: B-frags from pr
  #pragma unroll
  for(int ks=0;ks<4;ks++){
    int kb=ks*64+lg*16;
    bf[ks]=*(const short8*)(smem + ((ploc<<8) + (kb ^ psw)));
  }
  #pragma unroll
  for(int half=0;half<2;half++){
    f32x4 hacc[8];
    #pragma unroll
    for(int cb=0;cb<8;cb++){
      f32x4 a={0.f,0.f,0.f,0.f};
      #pragma unroll
      for(int ks=0;ks<4;ks++){
        short8 af=*(const short8*)(w1_f + (size_t)(((half*8+cb)*4+ks)*64+l)*8);
        a=__builtin_amdgcn_mfma_f32_16x16x32_bf16(af,bf[ks],a,0,0,0);
      }
      hacc[cb]=a;
    }
    // exact gelu + write hid
    #pragma unroll
    for(int cb=0;cb<8;cb++){
      int c0=(half*8+cb)*16+lg*4;
      float g0=hacc[cb][0], g1=hacc[cb][1], g2=hacc[cb][2], g3=hacc[cb][3];
      g0=0.5f*g0*(1.f+erff(g0*0.70710678118654752f));
      g1=0.5f*g1*(1.f+erff(g1*0.70710678118654752f));
      g2=0.5f*g2*(1.f+erff(g2*0.70710678118654752f));
      g3=0.5f*g3*(1.f+erff(g3*0.70710678118654752f));
      unsigned u01=(unsigned)f2us(g0) | (((unsigned)f2us(g1))<<16);
      unsigned u23=(unsigned)f2us(g2) | (((unsigned)f2us(g3))<<16);
      int base=16384 + (ploc<<9) + ((c0*2) ^ psw);
      *(unsigned*)(smem+base)=u01;
      *(unsigned*)(smem+base+4)=u23;
    }
  }
  // mlp2: B-frags from hid (K=256)
  short8 bf2[8];
  #pragma unroll
  for(int ks=0;ks<8;ks++){
    int kb=ks*64+lg*16;
    bf2[ks]=*(const short8*)(smem + (16384 + (ploc<<9) + (kb ^ psw)));
  }
  const int pg=rem0+ploc;
  #pragma unroll
  for(int cb=0;cb<8;cb++){
    f32x4 a={0.f,0.f,0.f,0.f};
    #pragma unroll
    for(int ks=0;ks<8;ks++){
      short8 af=*(const short8*)(w2_f + (size_t)((cb*8+ks)*64+l)*8);
      a=__builtin_amdgcn_mfma_f32_16x16x32_bf16(af,bf2[ks],a,0,0,0);
    }
    int c0=cb*16+lg*4;
    h2[(size_t)(b*CDIM+c0  )*HW+pg]=f2b(a[0]);
    h2[(size_t)(b*CDIM+c0+1)*HW+pg]=f2b(a[1]);
    h2[(size_t)(b*CDIM+c0+2)*HW+pg]=f2b(a[2]);
    h2[(size_t)(b*CDIM+c0+3)*HW+pg]=f2b(a[3]);
  }
}

// ---------------- K6: final depthwise 3x3 + residual ----------------
__global__ __launch_bounds__(256) void k_final(const bf16* __restrict__ h2, const float* __restrict__ x,
  const float* __restrict__ mdw, float* __restrict__ out)
{
  const int blk=blockIdx.x;               // (b*128+c)*256 + h
  const int h=blk&255, bc=blk>>8, c=bc&127;
  const int t=threadIdx.x;
  __shared__ float rr[3][264];
  const size_t base=(size_t)bc*HW;
  #pragma unroll
  for(int r=0;r<3;r++){
    int hr=h+r-1; float vv=0.f;
    if(hr>=0&&hr<Hh) vv=b2f(h2[base+(size_t)hr*Ww+t]);
    rr[r][t+1]=vv;
  }
  if(t==0){
    #pragma unroll
    for(int r=0;r<3;r++){ rr[r][0]=0.f; rr[r][257]=0.f; }
  }
  __syncthreads();
  const float* dwc=mdw+c*9;
  float acc = rr[0][t]*dwc[0]+rr[0][t+1]*dwc[1]+rr[0][t+2]*dwc[2]
            + rr[1][t]*dwc[3]+rr[1][t+1]*dwc[4]+rr[1][t+2]*dwc[5]
            + rr[2][t]*dwc[6]+rr[2][t+1]*dwc[7]+rr[2][t+2]*dwc[8];
  size_t o=base+(size_t)h*Ww+t;
  out[o]=acc+x[o];
}

// ---------------- workspace layout (bytes) ----------------
static const size_t O_INVR = 0;                       // 1 MiB  (B*HW f32)
static const size_t O_V    = (size_t)1<<20;           // 32 MiB bf16
static const size_t O_Q    = O_V    + (size_t)33554432;
static const size_t O_QPRE = O_Q    + (size_t)33554432;
static const size_t O_KPRE = O_QPRE + (size_t)33554432;
static const size_t O_XFSP = O_KPRE + (size_t)33554432; // 16 MiB bf16
static const size_t O_KV   = O_XFSP + (size_t)16777216;
static const size_t O_DEN  = O_KV   + 4096;
static const size_t O_PWF  = O_KV   + 8192;           // 32 KiB bf16 (proj frags)
static const size_t O_W1F  = O_PWF  + 32768;          // 64 KiB bf16 (w1 frags)
static const size_t O_W2F  = O_W1F  + 65536;          // 64 KiB bf16 (w2 frags)
static const size_t O_H2   = O_QPRE;                  // reuse qpre+kpre (64 MiB) for h2 bf16

extern "C" void kernel_launch(void* const* d_in, const int* in_sizes, int n_in,
                              void* d_out, int out_size, void* d_ws, size_t ws_size,
                              hipStream_t stream)
{
  const float* x     =(const float*)d_in[0];
  const float* n1s   =(const float*)d_in[1];
  const float* wq    =(const float*)d_in[2];
  const float* wk    =(const float*)d_in[3];
  const float* wv    =(const float*)d_in[4];
  const float* dwqk  =(const float*)d_in[5];
  const float* relb  =(const float*)d_in[6];
  const float* sscale=(const float*)d_in[7];
  const float* cw    =(const float*)d_in[8];
  const float* fnorm =(const float*)d_in[9];
  const float* freq_w=(const float*)d_in[10];
  const float* gate_w=(const float*)d_in[11];
  const float* projw =(const float*)d_in[12];
  const float* n2s   =(const float*)d_in[13];
  const float* w1    =(const float*)d_in[14];
  const float* w2    =(const float*)d_in[15];
  const float* mdw   =(const float*)d_in[16];

  char* ws=(char*)d_ws;
  float* invr =(float*)(ws+O_INVR);
  bf16* v    =(bf16*)(ws+O_V);
  bf16* q    =(bf16*)(ws+O_Q);
  bf16* qpre =(bf16*)(ws+O_QPRE);
  bf16* kpre =(bf16*)(ws+O_KPRE);
  bf16* xfsp =(bf16*)(ws+O_XFSP);
  float* kvsum=(float*)(ws+O_KV);
  float* densum=(float*)(ws+O_DEN);
  bf16* pw_f =(bf16*)(ws+O_PWF);
  bf16* w1_f =(bf16*)(ws+O_W1F);
  bf16* w2_f =(bf16*)(ws+O_W2F);
  bf16* h2   =(bf16*)(ws+O_H2);
  float* out =(float*)d_out;

  k_prep<<<dim3(320),dim3(256),0,stream>>>(projw,w1,w2,pw_f,w1_f,w2_f);
  k_invr<<<dim3(NPOS/256),dim3(256),0,stream>>>(x,invr);
  k_qkv<<<dim3(NPOS/64),dim3(256),0,stream>>>(x,invr,n1s,wq,wk,wv,qpre,kpre,v);
  hipMemsetAsync(ws+O_KV,0,8192,stream);
  k_spatial<<<dim3(B_*SD_*Hh),dim3(256),0,stream>>>(qpre,kpre,v,dwqk,q,kvsum,densum);
  k_hil<<<dim3(B_*FD_*Hh),dim3(256),0,stream>>>(x,invr,n1s,cw,xfsp);
  k_main<<<dim3(NPOS/64),dim3(256),0,stream>>>(x,invr,n1s,q,v,xfsp,kvsum,densum,
                                               relb,sscale,fnorm,freq_w,gate_w,pw_f,n2s,w1_f,w2_f,h2);
  k_final<<<dim3(B_*CDIM*Hh),dim3(256),0,stream>>>(h2,x,mdw,out);
}

// Round 10
// 765.204 us; speedup vs baseline: 3.9276x; 1.7536x over previous
//
#include <hip/hip_runtime.h>
#include <hip/hip_bf16.h>
#include <math.h>

#define B_    4
#define CDIM  128
#define Hh    256
#define Ww    256
#define SD_   64
#define FD_   32
#define HW    (Hh*Ww)
#define NPOS  (B_*HW)

typedef __hip_bfloat16 bf16;
typedef __attribute__((ext_vector_type(8))) short short8;
typedef __attribute__((ext_vector_type(4))) float f32x4;

__device__ __forceinline__ bf16 f2b(float f){ return __float2bfloat16(f); }
__device__ __forceinline__ float b2f(bf16 h){ return __bfloat162float(h); }
__device__ __forceinline__ unsigned short f2us(float f){
  __hip_bfloat16 h=__float2bfloat16(f);
  return *reinterpret_cast<unsigned short*>(&h);
}
__device__ __forceinline__ float us2f(unsigned short u){
  unsigned int i=((unsigned int)u)<<16;
  return __uint_as_float(i);
}

// ---------------- K0: repack weights into bf16 MFMA A-fragment order ----------------
// dst[((cb*NKS+ks)*64+lane)*8+e] = W[cb*16 + (lane&15)][ks*32 + (lane>>4)*8 + e]
__global__ __launch_bounds__(256) void k_prep(const float* __restrict__ projw,
   const float* __restrict__ w1, const float* __restrict__ w2,
   const float* __restrict__ wq, const float* __restrict__ wk, const float* __restrict__ wv,
   bf16* __restrict__ pw_f, bf16* __restrict__ w1_f, bf16* __restrict__ w2_f,
   bf16* __restrict__ wq_f, bf16* __restrict__ wk_f, bf16* __restrict__ wv_f)
{
  int idx=blockIdx.x*256+threadIdx.x;
  if(idx>=94208) return;
  const float* src; bf16* dst; int NKS,K,rel;
  if(idx<16384){ src=projw; dst=pw_f; NKS=4; K=128; rel=idx; }
  else if(idx<49152){ src=w1; dst=w1_f; NKS=4; K=128; rel=idx-16384; }
  else if(idx<81920){ src=w2; dst=w2_f; NKS=8; K=256; rel=idx-49152; }
  else if(idx<86016){ src=wq; dst=wq_f; NKS=2; K=64; rel=idx-81920; }
  else if(idx<90112){ src=wk; dst=wk_f; NKS=2; K=64; rel=idx-86016; }
  else { src=wv; dst=wv_f; NKS=2; K=64; rel=idx-90112; }
  int e=rel&7, lane=(rel>>3)&63, rest=rel>>9;
  int ks=rest%NKS, cb=rest/NKS;
  int row=cb*16+(lane&15);
  int k=ks*32+(lane>>4)*8+e;
  dst[rel]=f2b(src[row*K+k]);
}

// ---------------- K1: inverse RMS over 128 channels per position ----------------
__global__ __launch_bounds__(256) void k_invr(const float* __restrict__ x, float* __restrict__ invr){
  const int p=blockIdx.x*256+threadIdx.x;
  const int b=p/HW, rem=p-b*HW;
  const float* xp=x+(size_t)b*CDIM*HW+rem;
  float s=0.f;
  #pragma unroll 4
  for(int c=0;c<CDIM;c++){ float v=xp[(size_t)c*HW]; s+=v*v; }
  invr[p]=rsqrtf(s*(1.f/CDIM)+1e-6f);
}

// ---------------- K2: qpre/kpre/v via MFMA (64 pos/block, wave-private tail) ----------------
__global__ __launch_bounds__(256) void k_qkv(const float* __restrict__ x, const float* __restrict__ invr,
    const float* __restrict__ n1s, const bf16* __restrict__ wq_f, const bf16* __restrict__ wk_f,
    const bf16* __restrict__ wv_f,
    bf16* __restrict__ qpre, bf16* __restrict__ kpre, bf16* __restrict__ vout)
{
  __shared__ __align__(16) char smem[8192];   // [64 pos][64 ch] bf16, row 128B, XOR swizzle
  const int t=threadIdx.x;
  const int p0=blockIdx.x*64;
  const int b=p0/HW, rem0=p0-b*HW;
  for(int i=t;i<4096;i+=256){
    int ci=i>>6, p=i&63;
    float v_=x[(size_t)(b*CDIM+ci)*HW+rem0+p]*invr[p0+p]*n1s[ci];
    *(unsigned short*)(smem + (p<<7) + ((ci*2) ^ ((p&7)<<4))) = f2us(v_);
  }
  __syncthreads();
  const int l=t&63, w=t>>6;
  const int ploc=w*16+(l&15);
  const int lg=l>>4;
  const int psw=(ploc&7)<<4;
  short8 bfr[2];
  #pragma unroll
  for(int ks=0;ks<2;ks++){
    bfr[ks]=*(const short8*)(smem + (ploc<<7) + ((ks*64+lg*16) ^ psw));
  }
  const int pg=rem0+ploc;
  #pragma unroll
  for(int cb=0;cb<4;cb++){
    f32x4 aq={0.f,0.f,0.f,0.f}, ak={0.f,0.f,0.f,0.f}, av={0.f,0.f,0.f,0.f};
    #pragma unroll
    for(int ks=0;ks<2;ks++){
      short8 afq=*(const short8*)(wq_f + (size_t)((cb*2+ks)*64+l)*8);
      short8 afk=*(const short8*)(wk_f + (size_t)((cb*2+ks)*64+l)*8);
      short8 afv=*(const short8*)(wv_f + (size_t)((cb*2+ks)*64+l)*8);
      aq=__builtin_amdgcn_mfma_f32_16x16x32_bf16(afq,bfr[ks],aq,0,0,0);
      ak=__builtin_amdgcn_mfma_f32_16x16x32_bf16(afk,bfr[ks],ak,0,0,0);
      av=__builtin_amdgcn_mfma_f32_16x16x32_bf16(afv,bfr[ks],av,0,0,0);
    }
    int c0=cb*16+lg*4;
    #pragma unroll
    for(int j=0;j<4;j++){
      size_t off=(size_t)(b*SD_+c0+j)*HW+pg;
      qpre[off]=f2b(aq[j]); kpre[off]=f2b(ak[j]); vout[off]=f2b(av[j]);
    }
  }
}

// ---------------- K3: depthwise 3x3 + elu+1 + kv/denom reduce, 32-row h-tiles ----------------
__global__ __launch_bounds__(256) void k_spatial(const bf16* __restrict__ qpre, const bf16* __restrict__ kpre,
  const bf16* __restrict__ vin, const float* __restrict__ dwqk,
  bf16* __restrict__ qout, float* __restrict__ kvsum, float* __restrict__ densum)
{
  const int blk=blockIdx.x;            // bc*8 + tile
  const int tile=blk&7, bc=blk>>3, c=bc&63;
  const int h0=tile*32;
  const int t=threadIdx.x;             // = column w
  __shared__ unsigned short qs[34*256];
  __shared__ unsigned short ks_[34*256];
  __shared__ float pkv[4], pk[4];
  const size_t base=(size_t)bc*HW;
  for(int i=t;i<34*32;i+=256){
    int r=i>>5, c8=(i&31)<<3;
    int hr=h0+r-1;
    short8 zq={0,0,0,0,0,0,0,0}, zk={0,0,0,0,0,0,0,0};
    if(hr>=0&&hr<Hh){
      zq=*(const short8*)(qpre+base+(size_t)hr*Ww+c8);
      zk=*(const short8*)(kpre+base+(size_t)hr*Ww+c8);
    }
    *(short8*)(qs+r*256+c8)=zq;
    *(short8*)(ks_+r*256+c8)=zk;
  }
  __syncthreads();
  const float* dwc=dwqk+c*9;
  float d[9];
  #pragma unroll
  for(int j=0;j<9;j++) d[j]=dwc[j];
  float qw[3][3], kw[3][3];
  #pragma unroll
  for(int r=0;r<2;r++){
    qw[r][0]=(t>0)?us2f(qs[r*256+t-1]):0.f;
    qw[r][1]=us2f(qs[r*256+t]);
    qw[r][2]=(t<255)?us2f(qs[r*256+t+1]):0.f;
    kw[r][0]=(t>0)?us2f(ks_[r*256+t-1]):0.f;
    kw[r][1]=us2f(ks_[r*256+t]);
    kw[r][2]=(t<255)?us2f(ks_[r*256+t+1]):0.f;
  }
  float s1=0.f,s2=0.f;
  #pragma unroll
  for(int i=0;i<32;i++){
    const int rn=i+2, sn=(i+2)%3, sA=(i+1)%3, s0=i%3;
    qw[sn][0]=(t>0)?us2f(qs[rn*256+t-1]):0.f;
    qw[sn][1]=us2f(qs[rn*256+t]);
    qw[sn][2]=(t<255)?us2f(qs[rn*256+t+1]):0.f;
    kw[sn][0]=(t>0)?us2f(ks_[rn*256+t-1]):0.f;
    kw[sn][1]=us2f(ks_[rn*256+t]);
    kw[sn][2]=(t<255)?us2f(ks_[rn*256+t+1]):0.f;
    float qa=qw[s0][0]*d[0]+qw[s0][1]*d[1]+qw[s0][2]*d[2]
            +qw[sA][0]*d[3]+qw[sA][1]*d[4]+qw[sA][2]*d[5]
            +qw[sn][0]*d[6]+qw[sn][1]*d[7]+qw[sn][2]*d[8];
    float ka=kw[s0][0]*d[0]+kw[s0][1]*d[1]+kw[s0][2]*d[2]
            +kw[sA][0]*d[3]+kw[sA][1]*d[4]+kw[sA][2]*d[5]
            +kw[sn][0]*d[6]+kw[sn][1]*d[7]+kw[sn][2]*d[8];
    float qq=qa>0.f?qa+1.f:expf(qa);   // elu+1
    float kk=ka>0.f?ka+1.f:expf(ka);
    size_t o=base+(size_t)(h0+i)*Ww+t;
    qout[o]=f2b(qq);
    float vv=b2f(vin[o]);
    s1+=kk*vv; s2+=kk;
  }
  #pragma unroll
  for(int off=32;off>0;off>>=1){ s1+=__shfl_down(s1,off,64); s2+=__shfl_down(s2,off,64); }
  const int wid=t>>6, lane=t&63;
  if(lane==0){ pkv[wid]=s1; pk[wid]=s2; }
  __syncthreads();
  if(t==0){
    atomicAdd(&kvsum[bc], pkv[0]+pkv[1]+pkv[2]+pkv[3]);
    atomicAdd(&densum[bc], pk[0]+pk[1]+pk[2]+pk[3]);
  }
}

// ---------------- K4: frequency branch == a*x + b*rowHilbert(x) ----------------
__global__ __launch_bounds__(256) void k_hil(const float* __restrict__ x, const float* __restrict__ invr,
  const float* __restrict__ n1s, const float* __restrict__ cw, bf16* __restrict__ xfsp)
{
  const int blk=blockIdx.x;               // (b*32+cf)*256 + h
  const int h=blk&255, bcf=blk>>8, cf=bcf&31, b=bcf>>5;
  const int t=threadIdx.x;
  __shared__ float xr[256];
  __shared__ float tap[128];
  const int c=SD_+cf;
  const size_t rowx=(size_t)(b*CDIM+c)*HW+(size_t)h*Ww;
  const size_t rowp=(size_t)b*HW+(size_t)h*Ww;
  xr[t]=x[rowx+t]*invr[rowp+t]*n1s[c];
  if(t<128){
    int d=2*t+1;
    float dd = (d<128)? (float)d : (float)(256-d);
    float sg = (d<128)? -1.f : 1.f;
    float a=dd*(float)(3.14159265358979323846/256.0);
    tap[t]=sg*(1.f/128.f)*(cosf(a)/sinf(a));    // m[d] = -(2/W)cot(pi d/W), odd d
  }
  __syncthreads();
  float acc=0.f;
  #pragma unroll 8
  for(int j=0;j<128;j++){
    acc+=tap[j]*xr[(t-(2*j+1))&255];
  }
  float a_=cw[2*cf], b_=cw[2*cf+1];
  xfsp[(size_t)(b*FD_+cf)*HW+(size_t)h*Ww+t]=f2b(a_*xr[t]+b_*acc);
}

// ---------------- K5: gate + freq-norm + combine + MFMA proj/rmsnorm2/MLP ----------------
__global__ __launch_bounds__(256) void k_main(
  const float* __restrict__ x, const float* __restrict__ invr, const float* __restrict__ n1s,
  const bf16* __restrict__ q, const bf16* __restrict__ v, const bf16* __restrict__ xfsp,
  const float* __restrict__ kvsum, const float* __restrict__ densum,
  const float* __restrict__ relb, const float* __restrict__ sscale,
  const float* __restrict__ fnorm, const float* __restrict__ freq_w, const float* __restrict__ gate_w,
  const bf16* __restrict__ pw_f, const float* __restrict__ n2s,
  const bf16* __restrict__ w1_f, const bf16* __restrict__ w2_f,
  bf16* __restrict__ h2)
{
  __shared__ __align__(16) char smem[49152];
  float* xg  =(float*)(smem+16384);
  float* invp=(float*)(smem+24576);
  float* xfs =(float*)(smem+32768);
  float* gsh =(float*)(smem+40960);

  const int t=threadIdx.x;
  const int p0=blockIdx.x*64;
  const int b=p0/HW;
  const int rem0=p0-b*HW;

  for(int i=t;i<2048;i+=256){
    int ci=i>>6,p=i&63;
    xfs[i]=b2f(xfsp[(size_t)(b*FD_+ci)*HW+rem0+p]);
    xg[i] =x[(size_t)(b*CDIM+96+ci)*HW+rem0+p]*invr[p0+p]*n1s[96+ci];
  }
  __syncthreads();
  if(t<64){
    float s=0.f;
    #pragma unroll
    for(int ci=0;ci<32;ci++){ float vv=xfs[ci*64+t]; s+=vv*vv; }
    invp[t]=rsqrtf(s*(1.f/32.f)+1e-6f);
  }
  for(int i=t;i<2048;i+=256){
    int co=i>>6,p=i&63;
    int cou=__builtin_amdgcn_readfirstlane(co);
    float acc=0.f;
    #pragma unroll
    for(int ci=0;ci<32;ci+=4){
      float4 w4=*(const float4*)(gate_w+cou*32+ci);
      acc+=w4.x*xg[ci*64+p]+w4.y*xg[(ci+1)*64+p]+w4.z*xg[(ci+2)*64+p]+w4.w*xg[(ci+3)*64+p];
    }
    gsh[i]=1.f/(1.f+expf(-acc));
  }
  __syncthreads();
  for(int i=t;i<2048;i+=256){
    int ci=i>>6,p=i&63;
    xfs[i]*=invp[p]*fnorm[ci];
  }
  __syncthreads();
  const float ss=sscale[0];
  for(int i=t;i<8192;i+=256){
    int c=i>>6,p=i&63;
    float g=gsh[(c&31)*64+p];
    float val;
    if(c<64){
      size_t off=(size_t)(b*SD_+c)*HW+rem0+p;
      float kvv=kvsum[b*SD_+c];
      float dd=densum[b*SD_+c]+1e-6f;
      val=(b2f(q[off])*kvv/dd + b2f(v[off]))*(ss+relb[c]);
    } else if(c<96){
      int cou=__builtin_amdgcn_readfirstlane(c-64);
      float acc=0.f;
      #pragma unroll
      for(int ci=0;ci<32;ci+=4){
        float4 w4=*(const float4*)(freq_w+cou*32+ci);
        acc+=w4.x*xfs[ci*64+p]+w4.y*xfs[(ci+1)*64+p]+w4.z*xfs[(ci+2)*64+p]+w4.w*xfs[(ci+3)*64+p];
      }
      val=acc;
    } else {
      val=1.f;
    }
    *(unsigned short*)(smem + ((p<<8) + ((c*2) ^ ((p&7)<<4)))) = f2us(val*g);
  }
  __syncthreads();
  const int l=t&63, w=t>>6;
  const int ploc=w*16+(l&15);
  const int lg=l>>4;
  const int psw=(ploc&7)<<4;

  short8 bf[4];
  #pragma unroll
  for(int ks=0;ks<4;ks++){
    int kb=ks*64+lg*16;
    bf[ks]=*(const short8*)(smem + ((ploc<<8) + (kb ^ psw)));
  }
  f32x4 acc[8];
  #pragma unroll
  for(int cb=0;cb<8;cb++){
    f32x4 a={0.f,0.f,0.f,0.f};
    #pragma unroll
    for(int ks=0;ks<4;ks++){
      short8 af=*(const short8*)(pw_f + (size_t)((cb*4+ks)*64+l)*8);
      a=__builtin_amdgcn_mfma_f32_16x16x32_bf16(af,bf[ks],a,0,0,0);
    }
    acc[cb]=a;
  }
  float s2=0.f;
  #pragma unroll
  for(int cb=0;cb<8;cb++){
    s2+=acc[cb][0]*acc[cb][0]+acc[cb][1]*acc[cb][1]+acc[cb][2]*acc[cb][2]+acc[cb][3]*acc[cb][3];
  }
  s2+=__shfl_xor(s2,16);
  s2+=__shfl_xor(s2,32);
  float inv2=rsqrtf(s2*(1.f/128.f)+1e-6f);
  #pragma unroll
  for(int cb=0;cb<8;cb++){
    int c0=cb*16+lg*4;
    float4 nv=*(const float4*)(n2s+c0);
    float v0=acc[cb][0]*inv2*nv.x, v1=acc[cb][1]*inv2*nv.y;
    float v2=acc[cb][2]*inv2*nv.z, v3=acc[cb][3]*inv2*nv.w;
    unsigned u01=(unsigned)f2us(v0) | (((unsigned)f2us(v1))<<16);
    unsigned u23=(unsigned)f2us(v2) | (((unsigned)f2us(v3))<<16);
    int base=(ploc<<8) + ((c0*2) ^ psw);
    *(unsigned*)(smem+base)=u01;
    *(unsigned*)(smem+base+4)=u23;
  }
  #pragma unroll
  for(int ks=0;ks<4;ks++){
    int kb=ks*64+lg*16;
    bf[ks]=*(const short8*)(smem + ((ploc<<8) + (kb ^ psw)));
  }
  #pragma unroll
  for(int half=0;half<2;half++){
    f32x4 hacc[8];
    #pragma unroll
    for(int cb=0;cb<8;cb++){
      f32x4 a={0.f,0.f,0.f,0.f};
      #pragma unroll
      for(int ks=0;ks<4;ks++){
        short8 af=*(const short8*)(w1_f + (size_t)(((half*8+cb)*4+ks)*64+l)*8);
        a=__builtin_amdgcn_mfma_f32_16x16x32_bf16(af,bf[ks],a,0,0,0);
      }
      hacc[cb]=a;
    }
    #pragma unroll
    for(int cb=0;cb<8;cb++){
      int c0=(half*8+cb)*16+lg*4;
      float g0=hacc[cb][0], g1=hacc[cb][1], g2=hacc[cb][2], g3=hacc[cb][3];
      g0=0.5f*g0*(1.f+erff(g0*0.70710678118654752f));
      g1=0.5f*g1*(1.f+erff(g1*0.70710678118654752f));
      g2=0.5f*g2*(1.f+erff(g2*0.70710678118654752f));
      g3=0.5f*g3*(1.f+erff(g3*0.70710678118654752f));
      unsigned u01=(unsigned)f2us(g0) | (((unsigned)f2us(g1))<<16);
      unsigned u23=(unsigned)f2us(g2) | (((unsigned)f2us(g3))<<16);
      int base=16384 + (ploc<<9) + ((c0*2) ^ psw);
      *(unsigned*)(smem+base)=u01;
      *(unsigned*)(smem+base+4)=u23;
    }
  }
  short8 bf2[8];
  #pragma unroll
  for(int ks=0;ks<8;ks++){
    int kb=ks*64+lg*16;
    bf2[ks]=*(const short8*)(smem + (16384 + (ploc<<9) + (kb ^ psw)));
  }
  const int pg=rem0+ploc;
  #pragma unroll
  for(int cb=0;cb<8;cb++){
    f32x4 a={0.f,0.f,0.f,0.f};
    #pragma unroll
    for(int ks=0;ks<8;ks++){
      short8 af=*(const short8*)(w2_f + (size_t)((cb*8+ks)*64+l)*8);
      a=__builtin_amdgcn_mfma_f32_16x16x32_bf16(af,bf2[ks],a,0,0,0);
    }
    int c0=cb*16+lg*4;
    h2[(size_t)(b*CDIM+c0  )*HW+pg]=f2b(a[0]);
    h2[(size_t)(b*CDIM+c0+1)*HW+pg]=f2b(a[1]);
    h2[(size_t)(b*CDIM+c0+2)*HW+pg]=f2b(a[2]);
    h2[(size_t)(b*CDIM+c0+3)*HW+pg]=f2b(a[3]);
  }
}

// ---------------- K6: final depthwise 3x3 + residual, 32-row h-tiles ----------------
__global__ __launch_bounds__(256) void k_final(const bf16* __restrict__ h2, const float* __restrict__ x,
  const float* __restrict__ mdw, float* __restrict__ out)
{
  const int blk=blockIdx.x;            // bc*8 + tile
  const int tile=blk&7, bc=blk>>3, c=bc&127;
  const int h0=tile*32;
  const int t=threadIdx.x;
  __shared__ unsigned short hs[34*256];
  const size_t base=(size_t)bc*HW;
  for(int i=t;i<34*32;i+=256){
    int r=i>>5, c8=(i&31)<<3;
    int hr=h0+r-1;
    short8 z={0,0,0,0,0,0,0,0};
    if(hr>=0&&hr<Hh) z=*(const short8*)(h2+base+(size_t)hr*Ww+c8);
    *(short8*)(hs+r*256+c8)=z;
  }
  __syncthreads();
  const float* dwc=mdw+c*9;
  float d[9];
  #pragma unroll
  for(int j=0;j<9;j++) d[j]=dwc[j];
  float w_[3][3];
  #pragma unroll
  for(int r=0;r<2;r++){
    w_[r][0]=(t>0)?us2f(hs[r*256+t-1]):0.f;
    w_[r][1]=us2f(hs[r*256+t]);
    w_[r][2]=(t<255)?us2f(hs[r*256+t+1]):0.f;
  }
  #pragma unroll
  for(int i=0;i<32;i++){
    const int rn=i+2, sn=(i+2)%3, sA=(i+1)%3, s0=i%3;
    w_[sn][0]=(t>0)?us2f(hs[rn*256+t-1]):0.f;
    w_[sn][1]=us2f(hs[rn*256+t]);
    w_[sn][2]=(t<255)?us2f(hs[rn*256+t+1]):0.f;
    float acc=w_[s0][0]*d[0]+w_[s0][1]*d[1]+w_[s0][2]*d[2]
             +w_[sA][0]*d[3]+w_[sA][1]*d[4]+w_[sA][2]*d[5]
             +w_[sn][0]*d[6]+w_[sn][1]*d[7]+w_[sn][2]*d[8];
    size_t o=base+(size_t)(h0+i)*Ww+t;
    out[o]=acc+x[o];
  }
}

// ---------------- workspace layout (bytes) ----------------
static const size_t O_INVR = 0;                       // 1 MiB  (B*HW f32)
static const size_t O_V    = (size_t)1<<20;           // 32 MiB bf16
static const size_t O_Q    = O_V    + (size_t)33554432;
static const size_t O_QPRE = O_Q    + (size_t)33554432;
static const size_t O_KPRE = O_QPRE + (size_t)33554432;
static const size_t O_XFSP = O_KPRE + (size_t)33554432; // 16 MiB bf16
static const size_t O_KV   = O_XFSP + (size_t)16777216;
static const size_t O_DEN  = O_KV   + 4096;
static const size_t O_PWF  = O_KV   + 8192;           // 32 KiB bf16 (proj frags)
static const size_t O_W1F  = O_PWF  + 32768;          // 64 KiB bf16 (w1 frags)
static const size_t O_W2F  = O_W1F  + 65536;          // 64 KiB bf16 (w2 frags)
static const size_t O_WQF  = O_W2F  + 65536;          // 8 KiB
static const size_t O_WKF  = O_WQF  + 8192;           // 8 KiB
static const size_t O_WVF  = O_WKF  + 8192;           // 8 KiB
static const size_t O_H2   = O_QPRE;                  // reuse qpre+kpre (64 MiB) for h2 bf16

extern "C" void kernel_launch(void* const* d_in, const int* in_sizes, int n_in,
                              void* d_out, int out_size, void* d_ws, size_t ws_size,
                              hipStream_t stream)
{
  const float* x     =(const float*)d_in[0];
  const float* n1s   =(const float*)d_in[1];
  const float* wq    =(const float*)d_in[2];
  const float* wk    =(const float*)d_in[3];
  const float* wv    =(const float*)d_in[4];
  const float* dwqk  =(const float*)d_in[5];
  const float* relb  =(const float*)d_in[6];
  const float* sscale=(const float*)d_in[7];
  const float* cw    =(const float*)d_in[8];
  const float* fnorm =(const float*)d_in[9];
  const float* freq_w=(const float*)d_in[10];
  const float* gate_w=(const float*)d_in[11];
  const float* projw =(const float*)d_in[12];
  const float* n2s   =(const float*)d_in[13];
  const float* w1    =(const float*)d_in[14];
  const float* w2    =(const float*)d_in[15];
  const float* mdw   =(const float*)d_in[16];

  char* ws=(char*)d_ws;
  float* invr =(float*)(ws+O_INVR);
  bf16* v    =(bf16*)(ws+O_V);
  bf16* q    =(bf16*)(ws+O_Q);
  bf16* qpre =(bf16*)(ws+O_QPRE);
  bf16* kpre =(bf16*)(ws+O_KPRE);
  bf16* xfsp =(bf16*)(ws+O_XFSP);
  float* kvsum=(float*)(ws+O_KV);
  float* densum=(float*)(ws+O_DEN);
  bf16* pw_f =(bf16*)(ws+O_PWF);
  bf16* w1_f =(bf16*)(ws+O_W1F);
  bf16* w2_f =(bf16*)(ws+O_W2F);
  bf16* wq_f =(bf16*)(ws+O_WQF);
  bf16* wk_f =(bf16*)(ws+O_WKF);
  bf16* wv_f =(bf16*)(ws+O_WVF);
  bf16* h2   =(bf16*)(ws+O_H2);
  float* out =(float*)d_out;

  k_prep<<<dim3(368),dim3(256),0,stream>>>(projw,w1,w2,wq,wk,wv,pw_f,w1_f,w2_f,wq_f,wk_f,wv_f);
  k_invr<<<dim3(NPOS/256),dim3(256),0,stream>>>(x,invr);
  k_qkv<<<dim3(NPOS/64),dim3(256),0,stream>>>(x,invr,n1s,wq_f,wk_f,wv_f,qpre,kpre,v);
  hipMemsetAsync(ws+O_KV,0,8192,stream);
  k_spatial<<<dim3(B_*SD_*8),dim3(256),0,stream>>>(qpre,kpre,v,dwqk,q,kvsum,densum);
  k_hil<<<dim3(B_*FD_*Hh),dim3(256),0,stream>>>(x,invr,n1s,cw,xfsp);
  k_main<<<dim3(NPOS/64),dim3(256),0,stream>>>(x,invr,n1s,q,v,xfsp,kvsum,densum,
                                               relb,sscale,fnorm,freq_w,gate_w,pw_f,n2s,w1_f,w2_f,h2);
  k_final<<<dim3(B_*CDIM*8),dim3(256),0,stream>>>(h2,x,mdw,out);
}

// Round 11
// 655.817 us; speedup vs baseline: 4.5827x; 1.1668x over previous
//
#include <hip/hip_runtime.h>
#include <hip/hip_bf16.h>
#include <math.h>

#define B_    4
#define CDIM  128
#define Hh    256
#define Ww    256
#define SD_   64
#define FD_   32
#define HW    (Hh*Ww)
#define NPOS  (B_*HW)

typedef __hip_bfloat16 bf16;
typedef __attribute__((ext_vector_type(8))) short short8;
typedef __attribute__((ext_vector_type(4))) float f32x4;

__device__ __forceinline__ bf16 f2b(float f){ return __float2bfloat16(f); }
__device__ __forceinline__ float b2f(bf16 h){ return __bfloat162float(h); }
__device__ __forceinline__ unsigned short f2us(float f){
  __hip_bfloat16 h=__float2bfloat16(f);
  return *reinterpret_cast<unsigned short*>(&h);
}
__device__ __forceinline__ float us2f(unsigned short u){
  unsigned int i=((unsigned int)u)<<16;
  return __uint_as_float(i);
}
__device__ __forceinline__ float gelu_t(float x){
  float u=0.7978845608f*(x+0.044715f*x*x*x);
  float e=__expf(2.f*u);
  float th=1.f-2.f/(e+1.f);       // tanh(u), overflow-safe
  return 0.5f*x*(1.f+th);
}

// ---------------- K0: repack weights into bf16 MFMA A-fragment order ----------------
// dst[((cb*NKS+ks)*64+lane)*8+e] = W[cb*16 + (lane&15)][ks*32 + (lane>>4)*8 + e]
__global__ __launch_bounds__(256) void k_prep(const float* __restrict__ projw,
   const float* __restrict__ w1, const float* __restrict__ w2,
   const float* __restrict__ wq, const float* __restrict__ wk, const float* __restrict__ wv,
   const float* __restrict__ gatew, const float* __restrict__ freqw,
   bf16* __restrict__ pw_f, bf16* __restrict__ w1_f, bf16* __restrict__ w2_f,
   bf16* __restrict__ wq_f, bf16* __restrict__ wk_f, bf16* __restrict__ wv_f,
   bf16* __restrict__ gw_f, bf16* __restrict__ fw_f)
{
  int idx=blockIdx.x*256+threadIdx.x;
  if(idx>=96256) return;
  const float* src; bf16* dst; int NKS,K,rel;
  if(idx<16384){ src=projw; dst=pw_f; NKS=4; K=128; rel=idx; }
  else if(idx<49152){ src=w1; dst=w1_f; NKS=4; K=128; rel=idx-16384; }
  else if(idx<81920){ src=w2; dst=w2_f; NKS=8; K=256; rel=idx-49152; }
  else if(idx<86016){ src=wq; dst=wq_f; NKS=2; K=64; rel=idx-81920; }
  else if(idx<90112){ src=wk; dst=wk_f; NKS=2; K=64; rel=idx-86016; }
  else if(idx<94208){ src=wv; dst=wv_f; NKS=2; K=64; rel=idx-90112; }
  else if(idx<95232){ src=gatew; dst=gw_f; NKS=1; K=32; rel=idx-94208; }
  else { src=freqw; dst=fw_f; NKS=1; K=32; rel=idx-95232; }
  int e=rel&7, lane=(rel>>3)&63, rest=rel>>9;
  int ks=rest%NKS, cb=rest/NKS;
  int row=cb*16+(lane&15);
  int k=ks*32+(lane>>4)*8+e;
  dst[rel]=f2b(src[row*K+k]);
}

// ---------------- K1: fused invr + qkv MFMA (64 pos/block) ----------------
__global__ __launch_bounds__(256) void k_qkv(const float* __restrict__ x,
    const float* __restrict__ n1s, const bf16* __restrict__ wq_f, const bf16* __restrict__ wk_f,
    const bf16* __restrict__ wv_f,
    bf16* __restrict__ qpre, bf16* __restrict__ kpre, bf16* __restrict__ vout,
    float* __restrict__ invr)
{
  __shared__ float sqp[256];
  __shared__ float invl[64];
  __shared__ __align__(16) char qb[8192];   // [64 pos][64 ch] bf16, row 128B, XOR swizzle
  const int t=threadIdx.x;
  const int p0=blockIdx.x*64;
  const int b=p0/HW, rem0=p0-b*HW;
  const int p=t&63, g=t>>6;
  float xv[32];
  {
    float ss=0.f;
    const float* xbase = x + (size_t)(b*CDIM+g*32)*HW + rem0 + p;
    #pragma unroll
    for(int k=0;k<32;k++){ float v_=xbase[(size_t)k*HW]; xv[k]=v_; ss+=v_*v_; }
    sqp[t]=ss;
  }
  __syncthreads();
  if(t<64){
    float s=sqp[t]+sqp[64+t]+sqp[128+t]+sqp[192+t];
    float iv=rsqrtf(s*(1.f/128.f)+1e-6f);
    invl[t]=iv; invr[p0+t]=iv;
  }
  __syncthreads();
  if(g<2){
    float iv=invl[p];
    #pragma unroll
    for(int k=0;k<32;k++){
      int ci=g*32+k;
      *(unsigned short*)(qb + (p<<7) + ((ci*2) ^ ((p&7)<<4))) = f2us(xv[k]*iv*n1s[ci]);
    }
  }
  __syncthreads();
  const int l=t&63, w=t>>6;
  const int ploc=w*16+(l&15);
  const int lg=l>>4;
  const int psw=(ploc&7)<<4;
  short8 bfr[2];
  #pragma unroll
  for(int ks=0;ks<2;ks++){
    bfr[ks]=*(const short8*)(qb + (ploc<<7) + ((ks*64+lg*16) ^ psw));
  }
  const int pg=rem0+ploc;
  #pragma unroll
  for(int cb=0;cb<4;cb++){
    f32x4 aq={0.f,0.f,0.f,0.f}, ak={0.f,0.f,0.f,0.f}, av={0.f,0.f,0.f,0.f};
    #pragma unroll
    for(int ks=0;ks<2;ks++){
      short8 afq=*(const short8*)(wq_f + (size_t)((cb*2+ks)*64+l)*8);
      short8 afk=*(const short8*)(wk_f + (size_t)((cb*2+ks)*64+l)*8);
      short8 afv=*(const short8*)(wv_f + (size_t)((cb*2+ks)*64+l)*8);
      aq=__builtin_amdgcn_mfma_f32_16x16x32_bf16(afq,bfr[ks],aq,0,0,0);
      ak=__builtin_amdgcn_mfma_f32_16x16x32_bf16(afk,bfr[ks],ak,0,0,0);
      av=__builtin_amdgcn_mfma_f32_16x16x32_bf16(afv,bfr[ks],av,0,0,0);
    }
    int c0=cb*16+lg*4;
    #pragma unroll
    for(int j=0;j<4;j++){
      size_t off=(size_t)(b*SD_+c0+j)*HW+pg;
      qpre[off]=f2b(aq[j]); kpre[off]=f2b(ak[j]); vout[off]=f2b(av[j]);
    }
  }
}

// ---------------- K3: depthwise 3x3 + elu+1 + kv/denom reduce, 32-row h-tiles ----------------
__global__ __launch_bounds__(256) void k_spatial(const bf16* __restrict__ qpre, const bf16* __restrict__ kpre,
  const bf16* __restrict__ vin, const float* __restrict__ dwqk,
  bf16* __restrict__ qout, float* __restrict__ kvsum, float* __restrict__ densum)
{
  const int blk=blockIdx.x;            // bc*8 + tile
  const int tile=blk&7, bc=blk>>3, c=bc&63;
  const int h0=tile*32;
  const int t=threadIdx.x;             // = column w
  __shared__ unsigned short qs[34*256];
  __shared__ unsigned short ks_[34*256];
  __shared__ float pkv[4], pk[4];
  const size_t base=(size_t)bc*HW;
  for(int i=t;i<34*32;i+=256){
    int r=i>>5, c8=(i&31)<<3;
    int hr=h0+r-1;
    short8 zq={0,0,0,0,0,0,0,0}, zk={0,0,0,0,0,0,0,0};
    if(hr>=0&&hr<Hh){
      zq=*(const short8*)(qpre+base+(size_t)hr*Ww+c8);
      zk=*(const short8*)(kpre+base+(size_t)hr*Ww+c8);
    }
    *(short8*)(qs+r*256+c8)=zq;
    *(short8*)(ks_+r*256+c8)=zk;
  }
  __syncthreads();
  const float* dwc=dwqk+c*9;
  float d[9];
  #pragma unroll
  for(int j=0;j<9;j++) d[j]=dwc[j];
  float qw[3][3], kw[3][3];
  #pragma unroll
  for(int r=0;r<2;r++){
    qw[r][0]=(t>0)?us2f(qs[r*256+t-1]):0.f;
    qw[r][1]=us2f(qs[r*256+t]);
    qw[r][2]=(t<255)?us2f(qs[r*256+t+1]):0.f;
    kw[r][0]=(t>0)?us2f(ks_[r*256+t-1]):0.f;
    kw[r][1]=us2f(ks_[r*256+t]);
    kw[r][2]=(t<255)?us2f(ks_[r*256+t+1]):0.f;
  }
  float s1=0.f,s2=0.f;
  #pragma unroll
  for(int i=0;i<32;i++){
    const int rn=i+2, sn=(i+2)%3, sA=(i+1)%3, s0=i%3;
    qw[sn][0]=(t>0)?us2f(qs[rn*256+t-1]):0.f;
    qw[sn][1]=us2f(qs[rn*256+t]);
    qw[sn][2]=(t<255)?us2f(qs[rn*256+t+1]):0.f;
    kw[sn][0]=(t>0)?us2f(ks_[rn*256+t-1]):0.f;
    kw[sn][1]=us2f(ks_[rn*256+t]);
    kw[sn][2]=(t<255)?us2f(ks_[rn*256+t+1]):0.f;
    float qa=qw[s0][0]*d[0]+qw[s0][1]*d[1]+qw[s0][2]*d[2]
            +qw[sA][0]*d[3]+qw[sA][1]*d[4]+qw[sA][2]*d[5]
            +qw[sn][0]*d[6]+qw[sn][1]*d[7]+qw[sn][2]*d[8];
    float ka=kw[s0][0]*d[0]+kw[s0][1]*d[1]+kw[s0][2]*d[2]
            +kw[sA][0]*d[3]+kw[sA][1]*d[4]+kw[sA][2]*d[5]
            +kw[sn][0]*d[6]+kw[sn][1]*d[7]+kw[sn][2]*d[8];
    float qq=qa>0.f?qa+1.f:__expf(qa);   // elu+1
    float kk=ka>0.f?ka+1.f:__expf(ka);
    size_t o=base+(size_t)(h0+i)*Ww+t;
    qout[o]=f2b(qq);
    float vv=b2f(vin[o]);
    s1+=kk*vv; s2+=kk;
  }
  #pragma unroll
  for(int off=32;off>0;off>>=1){ s1+=__shfl_down(s1,off,64); s2+=__shfl_down(s2,off,64); }
  const int wid=t>>6, lane=t&63;
  if(lane==0){ pkv[wid]=s1; pk[wid]=s2; }
  __syncthreads();
  if(t==0){
    atomicAdd(&kvsum[bc], pkv[0]+pkv[1]+pkv[2]+pkv[3]);
    atomicAdd(&densum[bc], pk[0]+pk[1]+pk[2]+pk[3]);
  }
}

// ---------------- K4: frequency branch == a*x + b*rowHilbert(x), 8 rows/block ----------------
__global__ __launch_bounds__(256) void k_hil(const float* __restrict__ x, const float* __restrict__ invr,
  const float* __restrict__ n1s, const float* __restrict__ cw, bf16* __restrict__ xfsp)
{
  const int blk=blockIdx.x;               // (b*32+cf)*32 + tile
  const int tile=blk&31, bcf=blk>>5, cf=bcf&31, b=bcf>>5;
  const int h0=tile*8;
  const int t=threadIdx.x;
  __shared__ float xr[8*256];
  __shared__ float tap[128];
  const int c=SD_+cf;
  const size_t rowx=(size_t)(b*CDIM+c)*HW+(size_t)h0*Ww;
  const size_t rowp=(size_t)b*HW+(size_t)h0*Ww;
  const float nsc=n1s[c];
  #pragma unroll
  for(int k=0;k<8;k++){
    int i=t+k*256;
    xr[i]=x[rowx+i]*invr[rowp+i]*nsc;
  }
  if(t<128){
    int d=2*t+1;
    float dd = (d<128)? (float)d : (float)(256-d);
    float sg = (d<128)? -1.f : 1.f;
    float a=dd*(float)(3.14159265358979323846/256.0);
    tap[t]=sg*(1.f/128.f)*(cosf(a)/sinf(a));    // m[d] = -(2/W)cot(pi d/W), odd d
  }
  __syncthreads();
  float a_=cw[2*cf], b_=cw[2*cf+1];
  #pragma unroll
  for(int r=0;r<8;r++){
    float acc=0.f;
    #pragma unroll 8
    for(int j=0;j<128;j++){
      acc+=tap[j]*xr[r*256 + ((t-(2*j+1))&255)];
    }
    xfsp[(size_t)(b*FD_+cf)*HW+(size_t)(h0+r)*Ww+t]=f2b(a_*xr[r*256+t]+b_*acc);
  }
}

// ---------------- K5: gate/freq MFMA + combine + MFMA proj/rmsnorm2/MLP ----------------
// LDS (32KB): comb/pr [64pos][128ch] bf16 swz @0..16K
//   region B @16K..32K: front {sqp 1K @16384, invp @17408, xgb 4K @18432,
//   xfsb 4K @22528, gsh 4K @26624}; then hid [64pos][128ch] bf16 @16384 (16K)
__global__ __launch_bounds__(256) void k_main(
  const float* __restrict__ x, const float* __restrict__ invr, const float* __restrict__ n1s,
  const bf16* __restrict__ q, const bf16* __restrict__ v, const bf16* __restrict__ xfsp,
  const float* __restrict__ kvsum, const float* __restrict__ densum,
  const float* __restrict__ relb, const float* __restrict__ sscale,
  const float* __restrict__ fnorm, const bf16* __restrict__ fw_f, const bf16* __restrict__ gw_f,
  const bf16* __restrict__ pw_f, const float* __restrict__ n2s,
  const bf16* __restrict__ w1_f, const bf16* __restrict__ w2_f,
  bf16* __restrict__ h2)
{
  __shared__ __align__(16) char smem[32768];
  float* sqp =(float*)(smem+16384);
  float* invp=(float*)(smem+17408);

  const int t=threadIdx.x;
  const int p0=blockIdx.x*64;
  const int b=p0/HW;
  const int rem0=p0-b*HW;
  const int l=t&63, w=t>>6;
  const int ploc=w*16+(l&15);
  const int lg=l>>4;
  const int psw=(ploc&7)<<4;

  // P1: xfsp -> xv regs + ssq partial; x-gate -> xgb (swz bf16)
  float xv[8];
  {
    const int p=t&63, g=t>>6;
    float ss=0.f;
    #pragma unroll
    for(int k=0;k<8;k++){
      int ci=g*8+k;
      float v_=b2f(xfsp[(size_t)(b*FD_+ci)*HW+rem0+p]);
      xv[k]=v_; ss+=v_*v_;
    }
    sqp[t]=ss;
    float iv=invr[p0+p];
    #pragma unroll
    for(int k=0;k<8;k++){
      int ci=g*8+k;
      float gv=x[(size_t)(b*CDIM+96+ci)*HW+rem0+p]*iv*n1s[96+ci];
      *(unsigned short*)(smem + 18432 + (p<<6) + ((ci*2) ^ ((p&3)<<4))) = f2us(gv);
    }
  }
  __syncthreads();
  // P2: invp; gate MFMA -> sigmoid -> gsh (bf16 [32][64])
  if(t<64){
    float s=sqp[t]+sqp[64+t]+sqp[128+t]+sqp[192+t];
    invp[t]=rsqrtf(s*(1.f/32.f)+1e-6f);
  }
  {
    short8 bg=*(const short8*)(smem + 18432 + (ploc<<6) + ((lg*16) ^ ((ploc&3)<<4)));
    #pragma unroll
    for(int cb=0;cb<2;cb++){
      short8 ag=*(const short8*)(gw_f + (size_t)(cb*64+l)*8);
      f32x4 a={0.f,0.f,0.f,0.f};
      a=__builtin_amdgcn_mfma_f32_16x16x32_bf16(ag,bg,a,0,0,0);
      #pragma unroll
      for(int j=0;j<4;j++){
        int cch=cb*16+lg*4+j;
        float gj=1.f/(1.f+__expf(-a[j]));
        *(unsigned short*)(smem + 26624 + cch*128 + ploc*2) = f2us(gj);
      }
    }
  }
  __syncthreads();
  // P3: fold fnorm rms -> xfsb (swz bf16)
  {
    const int p=t&63, g=t>>6;
    float iv=invp[p];
    #pragma unroll
    for(int k=0;k<8;k++){
      int ci=g*8+k;
      *(unsigned short*)(smem + 22528 + (p<<6) + ((ci*2) ^ ((p&3)<<4))) = f2us(xv[k]*iv*fnorm[ci]);
    }
  }
  __syncthreads();
  // P4: freq MFMA -> gated comb[64..95] (wave-private rows); combine c in {0..63,96..127}
  {
    short8 bff=*(const short8*)(smem + 22528 + (ploc<<6) + ((lg*16) ^ ((ploc&3)<<4)));
    #pragma unroll
    for(int cb=0;cb<2;cb++){
      short8 af=*(const short8*)(fw_f + (size_t)(cb*64+l)*8);
      f32x4 a={0.f,0.f,0.f,0.f};
      a=__builtin_amdgcn_mfma_f32_16x16x32_bf16(af,bff,a,0,0,0);
      #pragma unroll
      for(int j=0;j<4;j++){
        int cf=cb*16+lg*4+j;
        float gj=us2f(*(const unsigned short*)(smem + 26624 + cf*128 + ploc*2));
        int c=64+cf;
        *(unsigned short*)(smem + (ploc<<8) + ((c*2) ^ psw)) = f2us(a[j]*gj);
      }
    }
  }
  const float ss=sscale[0];
  for(int i=t;i<6144;i+=256){
    int cc=i>>6, p=i&63;
    int c=(cc<64)? cc : cc+32;
    float g=us2f(*(const unsigned short*)(smem + 26624 + (c&31)*128 + p*2));
    float val;
    if(c<64){
      size_t off=(size_t)(b*SD_+c)*HW+rem0+p;
      float kvv=kvsum[b*SD_+c];
      float dd=densum[b*SD_+c]+1e-6f;
      val=(b2f(q[off])*kvv/dd + b2f(v[off]))*(ss+relb[c]);
    } else {
      val=1.f;
    }
    *(unsigned short*)(smem + (p<<8) + ((c*2) ^ ((p&7)<<4))) = f2us(val*g);
  }
  __syncthreads();
  // ---- wave-private MFMA tail ----
  short8 bf[4];
  #pragma unroll
  for(int ks=0;ks<4;ks++){
    bf[ks]=*(const short8*)(smem + (ploc<<8) + (((ks*64+lg*16)) ^ psw));
  }
  f32x4 acc[8];
  #pragma unroll
  for(int cb=0;cb<8;cb++){
    f32x4 a={0.f,0.f,0.f,0.f};
    #pragma unroll
    for(int ks=0;ks<4;ks++){
      short8 af=*(const short8*)(pw_f + (size_t)((cb*4+ks)*64+l)*8);
      a=__builtin_amdgcn_mfma_f32_16x16x32_bf16(af,bf[ks],a,0,0,0);
    }
    acc[cb]=a;
  }
  float s2=0.f;
  #pragma unroll
  for(int cb=0;cb<8;cb++){
    s2+=acc[cb][0]*acc[cb][0]+acc[cb][1]*acc[cb][1]+acc[cb][2]*acc[cb][2]+acc[cb][3]*acc[cb][3];
  }
  s2+=__shfl_xor(s2,16);
  s2+=__shfl_xor(s2,32);
  float inv2=rsqrtf(s2*(1.f/128.f)+1e-6f);
  #pragma unroll
  for(int cb=0;cb<8;cb++){
    int c0=cb*16+lg*4;
    float4 nv=*(const float4*)(n2s+c0);
    float v0=acc[cb][0]*inv2*nv.x, v1=acc[cb][1]*inv2*nv.y;
    float v2=acc[cb][2]*inv2*nv.z, v3=acc[cb][3]*inv2*nv.w;
    unsigned u01=(unsigned)f2us(v0) | (((unsigned)f2us(v1))<<16);
    unsigned u23=(unsigned)f2us(v2) | (((unsigned)f2us(v3))<<16);
    int base=(ploc<<8) + ((c0*2) ^ psw);
    *(unsigned*)(smem+base)=u01;
    *(unsigned*)(smem+base+4)=u23;
  }
  #pragma unroll
  for(int ks=0;ks<4;ks++){
    bf[ks]=*(const short8*)(smem + (ploc<<8) + (((ks*64+lg*16)) ^ psw));
  }
  // mlp1/mlp2 interleaved halves; hid = region B @16384, [64pos][128ch] bf16, wave-private rows
  f32x4 acc2[8];
  #pragma unroll
  for(int cb=0;cb<8;cb++){ acc2[cb]=(f32x4){0.f,0.f,0.f,0.f}; }
  #pragma unroll
  for(int half=0;half<2;half++){
    #pragma unroll
    for(int cb=0;cb<8;cb++){
      f32x4 a={0.f,0.f,0.f,0.f};
      #pragma unroll
      for(int ks=0;ks<4;ks++){
        short8 af=*(const short8*)(w1_f + (size_t)(((half*8+cb)*4+ks)*64+l)*8);
        a=__builtin_amdgcn_mfma_f32_16x16x32_bf16(af,bf[ks],a,0,0,0);
      }
      int c0=cb*16+lg*4;    // channel within half
      float g0=gelu_t(a[0]), g1=gelu_t(a[1]), g2=gelu_t(a[2]), g3=gelu_t(a[3]);
      unsigned u01=(unsigned)f2us(g0) | (((unsigned)f2us(g1))<<16);
      unsigned u23=(unsigned)f2us(g2) | (((unsigned)f2us(g3))<<16);
      int base=16384 + (ploc<<8) + ((c0*2) ^ psw);
      *(unsigned*)(smem+base)=u01;
      *(unsigned*)(smem+base+4)=u23;
    }
    #pragma unroll
    for(int ks=0;ks<4;ks++){
      short8 bh=*(const short8*)(smem + 16384 + (ploc<<8) + (((ks*64+lg*16)) ^ psw));
      #pragma unroll
      for(int cb=0;cb<8;cb++){
        short8 af=*(const short8*)(w2_f + (size_t)((cb*8+half*4+ks)*64+l)*8);
        acc2[cb]=__builtin_amdgcn_mfma_f32_16x16x32_bf16(af,bh,acc2[cb],0,0,0);
      }
    }
  }
  const int pg=rem0+ploc;
  #pragma unroll
  for(int cb=0;cb<8;cb++){
    int c0=cb*16+lg*4;
    h2[(size_t)(b*CDIM+c0  )*HW+pg]=f2b(acc2[cb][0]);
    h2[(size_t)(b*CDIM+c0+1)*HW+pg]=f2b(acc2[cb][1]);
    h2[(size_t)(b*CDIM+c0+2)*HW+pg]=f2b(acc2[cb][2]);
    h2[(size_t)(b*CDIM+c0+3)*HW+pg]=f2b(acc2[cb][3]);
  }
}

// ---------------- K6: final depthwise 3x3 + residual, 32-row h-tiles ----------------
__global__ __launch_bounds__(256) void k_final(const bf16* __restrict__ h2, const float* __restrict__ x,
  const float* __restrict__ mdw, float* __restrict__ out)
{
  const int blk=blockIdx.x;            // bc*8 + tile
  const int tile=blk&7, bc=blk>>3, c=bc&127;
  const int h0=tile*32;
  const int t=threadIdx.x;
  __shared__ unsigned short hs[34*256];
  const size_t base=(size_t)bc*HW;
  for(int i=t;i<34*32;i+=256){
    int r=i>>5, c8=(i&31)<<3;
    int hr=h0+r-1;
    short8 z={0,0,0,0,0,0,0,0};
    if(hr>=0&&hr<Hh) z=*(const short8*)(h2+base+(size_t)hr*Ww+c8);
    *(short8*)(hs+r*256+c8)=z;
  }
  __syncthreads();
  const float* dwc=mdw+c*9;
  float d[9];
  #pragma unroll
  for(int j=0;j<9;j++) d[j]=dwc[j];
  float w_[3][3];
  #pragma unroll
  for(int r=0;r<2;r++){
    w_[r][0]=(t>0)?us2f(hs[r*256+t-1]):0.f;
    w_[r][1]=us2f(hs[r*256+t]);
    w_[r][2]=(t<255)?us2f(hs[r*256+t+1]):0.f;
  }
  #pragma unroll
  for(int i=0;i<32;i++){
    const int rn=i+2, sn=(i+2)%3, sA=(i+1)%3, s0=i%3;
    w_[sn][0]=(t>0)?us2f(hs[rn*256+t-1]):0.f;
    w_[sn][1]=us2f(hs[rn*256+t]);
    w_[sn][2]=(t<255)?us2f(hs[rn*256+t+1]):0.f;
    float acc=w_[s0][0]*d[0]+w_[s0][1]*d[1]+w_[s0][2]*d[2]
             +w_[sA][0]*d[3]+w_[sA][1]*d[4]+w_[sA][2]*d[5]
             +w_[sn][0]*d[6]+w_[sn][1]*d[7]+w_[sn][2]*d[8];
    size_t o=base+(size_t)(h0+i)*Ww+t;
    out[o]=acc+x[o];
  }
}

// ---------------- workspace layout (bytes) ----------------
static const size_t O_INVR = 0;                       // 1 MiB  (B*HW f32)
static const size_t O_V    = (size_t)1<<20;           // 32 MiB bf16
static const size_t O_Q    = O_V    + (size_t)33554432;
static const size_t O_QPRE = O_Q    + (size_t)33554432;
static const size_t O_KPRE = O_QPRE + (size_t)33554432;
static const size_t O_XFSP = O_KPRE + (size_t)33554432; // 16 MiB bf16
static const size_t O_KV   = O_XFSP + (size_t)16777216;
static const size_t O_DEN  = O_KV   + 4096;
static const size_t O_PWF  = O_KV   + 8192;           // 32 KiB
static const size_t O_W1F  = O_PWF  + 32768;          // 64 KiB
static const size_t O_W2F  = O_W1F  + 65536;          // 64 KiB
static const size_t O_WQF  = O_W2F  + 65536;          // 8 KiB
static const size_t O_WKF  = O_WQF  + 8192;           // 8 KiB
static const size_t O_WVF  = O_WKF  + 8192;           // 8 KiB
static const size_t O_GWF  = O_WVF  + 8192;           // 2 KiB
static const size_t O_FWF  = O_GWF  + 2048;           // 2 KiB
static const size_t O_H2   = O_QPRE;                  // reuse qpre+kpre for h2 bf16

extern "C" void kernel_launch(void* const* d_in, const int* in_sizes, int n_in,
                              void* d_out, int out_size, void* d_ws, size_t ws_size,
                              hipStream_t stream)
{
  const float* x     =(const float*)d_in[0];
  const float* n1s   =(const float*)d_in[1];
  const float* wq    =(const float*)d_in[2];
  const float* wk    =(const float*)d_in[3];
  const float* wv    =(const float*)d_in[4];
  const float* dwqk  =(const float*)d_in[5];
  const float* relb  =(const float*)d_in[6];
  const float* sscale=(const float*)d_in[7];
  const float* cw    =(const float*)d_in[8];
  const float* fnorm =(const float*)d_in[9];
  const float* freq_w=(const float*)d_in[10];
  const float* gate_w=(const float*)d_in[11];
  const float* projw =(const float*)d_in[12];
  const float* n2s   =(const float*)d_in[13];
  const float* w1    =(const float*)d_in[14];
  const float* w2    =(const float*)d_in[15];
  const float* mdw   =(const float*)d_in[16];

  char* ws=(char*)d_ws;
  float* invr =(float*)(ws+O_INVR);
  bf16* v    =(bf16*)(ws+O_V);
  bf16* q    =(bf16*)(ws+O_Q);
  bf16* qpre =(bf16*)(ws+O_QPRE);
  bf16* kpre =(bf16*)(ws+O_KPRE);
  bf16* xfsp =(bf16*)(ws+O_XFSP);
  float* kvsum=(float*)(ws+O_KV);
  float* densum=(float*)(ws+O_DEN);
  bf16* pw_f =(bf16*)(ws+O_PWF);
  bf16* w1_f =(bf16*)(ws+O_W1F);
  bf16* w2_f =(bf16*)(ws+O_W2F);
  bf16* wq_f =(bf16*)(ws+O_WQF);
  bf16* wk_f =(bf16*)(ws+O_WKF);
  bf16* wv_f =(bf16*)(ws+O_WVF);
  bf16* gw_f =(bf16*)(ws+O_GWF);
  bf16* fw_f =(bf16*)(ws+O_FWF);
  bf16* h2   =(bf16*)(ws+O_H2);
  float* out =(float*)d_out;

  k_prep<<<dim3(376),dim3(256),0,stream>>>(projw,w1,w2,wq,wk,wv,gate_w,freq_w,
                                           pw_f,w1_f,w2_f,wq_f,wk_f,wv_f,gw_f,fw_f);
  k_qkv<<<dim3(NPOS/64),dim3(256),0,stream>>>(x,n1s,wq_f,wk_f,wv_f,qpre,kpre,v,invr);
  hipMemsetAsync(ws+O_KV,0,8192,stream);
  k_spatial<<<dim3(B_*SD_*8),dim3(256),0,stream>>>(qpre,kpre,v,dwqk,q,kvsum,densum);
  k_hil<<<dim3(B_*FD_*32),dim3(256),0,stream>>>(x,invr,n1s,cw,xfsp);
  k_main<<<dim3(NPOS/64),dim3(256),0,stream>>>(x,invr,n1s,q,v,xfsp,kvsum,densum,
                                               relb,sscale,fnorm,fw_f,gw_f,pw_f,n2s,w1_f,w2_f,h2);
  k_final<<<dim3(B_*CDIM*8),dim3(256),0,stream>>>(h2,x,mdw,out);
}